// Round 3
// baseline (430.971 us; speedup 1.0000x reference)
//
#include <hip/hip_runtime.h>
#include <math.h>

#define B_ROWS 512
#define D_DIM  512
#define C_CLS  100000
#define SCALE  64.0f
#define EPSN   1e-12f

#define BM 256
#define BN 64
#define BK 32
#define NKT (D_DIM / BK)    // 16
#define NTILE 1563          // ceil(100000/64)
#define NT2   (NTILE * 2)   // 32-class partial groups per row

typedef __attribute__((ext_vector_type(8))) short bf16x8;
typedef __attribute__((ext_vector_type(4))) float f32x4;

__device__ inline unsigned short f2bf(float f) {
    union { float f; unsigned int u; } v; v.f = f;
    unsigned int r = v.u + 0x7fffu + ((v.u >> 16) & 1u);
    return (unsigned short)(r >> 16);
}
__device__ inline float bf2f(unsigned short h) {
    union { unsigned int u; float f; } v; v.u = ((unsigned int)h) << 16;
    return v.f;
}

// ---------- normalize x rows, store bf16 (coalesced: lane, lane+64) ----------
__global__ void normalize_x(const float* __restrict__ x, unsigned short* __restrict__ xnb) {
    int row  = blockIdx.x;
    int lane = threadIdx.x;  // 64
    const float4* xr = (const float4*)(x + (size_t)row * D_DIM);
    float4 a = xr[lane];
    float4 b = xr[lane + 64];
    float ss = a.x*a.x + a.y*a.y + a.z*a.z + a.w*a.w
             + b.x*b.x + b.y*b.y + b.z*b.z + b.w*b.w;
    #pragma unroll
    for (int m = 1; m < 64; m <<= 1) ss += __shfl_xor(ss, m);
    float inv = 1.0f / fmaxf(sqrtf(ss), EPSN);
    ushort4 o0, o1;
    o0.x = f2bf(a.x*inv); o0.y = f2bf(a.y*inv); o0.z = f2bf(a.z*inv); o0.w = f2bf(a.w*inv);
    o1.x = f2bf(b.x*inv); o1.y = f2bf(b.y*inv); o1.z = f2bf(b.z*inv); o1.w = f2bf(b.w*inv);
    ushort4* orow = (ushort4*)(xnb + (size_t)row * D_DIM);
    orow[lane]      = o0;
    orow[lane + 64] = o1;
}

// ---------- fused GEMM: low-pressure geometry (no spill) ----------
// Block: BM=256 x BN=64, 512 threads = 8 waves split 4M x 2N -> wave tile 64x32.
// acc = 4x2 f32x4 = 32 AGPR; arch regs ~60 -> fits 128-cap at 4 waves/SIMD, 2 blocks/CU.
// W read twice total (grid.x=2 M-halves; pair-adjacent dispatch -> 2nd read L3-hot).
// Pipeline per K-step t: issue stage(t+1) [A via global_load_lds, W from reg prefetched
// at t-1] -> compute t -> ONE syncthreads.
__global__ __launch_bounds__(512, 4) void gemm_fused(const unsigned short* __restrict__ xnb,
                                                     const float* __restrict__ w,
                                                     float2* __restrict__ partials) {
    __shared__ unsigned short As[2 * BM * BK];   // 32 KB (2 x 16 KB)
    __shared__ unsigned short Bs[2 * BN * BK];   // 8 KB  (2 x 4 KB)
    __shared__ float winv_s[BN];

    int tid  = threadIdx.x;
    int m0   = blockIdx.x * BM;
    int c0   = blockIdx.y * BN;
    int wid  = tid >> 6;     // 0..7
    int lane = tid & 63;
    int quad = lane >> 4;
    int lr   = lane & 15;
    int wr   = wid >> 1;     // 0..3 : M quarter (64 rows)
    int wc   = wid & 1;      // 0..1 : N half (32 cols)

    f32x4 acc[4][2];
    #pragma unroll
    for (int i = 0; i < 4; i++)
        #pragma unroll
        for (int j = 0; j < 2; j++) {
            acc[i][j][0] = 0.f; acc[i][j][1] = 0.f; acc[i][j][2] = 0.f; acc[i][j][3] = 0.f;
        }

    // B staging: thread owns class row br (8 threads/row), float4 chunk bq
    int br = tid >> 3;           // 0..63
    int bq = tid & 7;            // 0..7
    int bc = c0 + br; if (bc >= C_CLS) bc = C_CLS - 1;
    const float* wsrc = w + (size_t)bc * D_DIM + bq * 4;

    // A staging: chunk ch = i*512 + tid; row = ch>>2 (0..255), koff = (ch&3)*8 ushorts
    const unsigned short* asrc[2];
    #pragma unroll
    for (int i = 0; i < 2; i++) {
        int ch = i * 512 + tid;
        asrc[i] = xnb + (size_t)(m0 + (ch >> 2)) * D_DIM + (ch & 3) * 8;
    }

    float ss = 0.f;

    // ---- prologue: stage tile 0 into buffer 0, prefetch W k-slice 1 into reg ----
    #pragma unroll
    for (int i = 0; i < 2; i++)
        __builtin_amdgcn_global_load_lds(
            (const __attribute__((address_space(1))) void*)(asrc[i]),
            (__attribute__((address_space(3))) void*)(As + (i * 512 + wid * 64) * 8),
            16, 0, 0);
    {
        float4 wv = *(const float4*)(wsrc);
        ss += wv.x*wv.x + wv.y*wv.y + wv.z*wv.z + wv.w*wv.w;
        ushort4 o;
        o.x = f2bf(wv.x); o.y = f2bf(wv.y); o.z = f2bf(wv.z); o.w = f2bf(wv.w);
        *(ushort4*)(Bs + br * BK + bq * 4) = o;
    }
    float4 wvn = *(const float4*)(wsrc + BK);
    __syncthreads();

    for (int t = 0; t < NKT; ++t) {
        int cur = t & 1, nxt = cur ^ 1;
        if (t + 1 < NKT) {
            int k1 = (t + 1) * BK;
            #pragma unroll
            for (int i = 0; i < 2; i++)
                __builtin_amdgcn_global_load_lds(
                    (const __attribute__((address_space(1))) void*)(asrc[i] + k1),
                    (__attribute__((address_space(3))) void*)(As + nxt * 8192 + (i * 512 + wid * 64) * 8),
                    16, 0, 0);
            float4 wv = wvn;                       // W[t+1], loaded one iteration ago
            if (t + 2 < NKT) wvn = *(const float4*)(wsrc + (t + 2) * BK);
            ss += wv.x*wv.x + wv.y*wv.y + wv.z*wv.z + wv.w*wv.w;
            ushort4 o;
            o.x = f2bf(wv.x); o.y = f2bf(wv.y); o.z = f2bf(wv.z); o.w = f2bf(wv.w);
            *(ushort4*)(Bs + nxt * 2048 + br * BK + bq * 4) = o;
        }
        // ---- compute tile t from buf cur ----
        bf16x8 af[4], bf[2];
        #pragma unroll
        for (int i = 0; i < 4; i++)
            af[i] = *(const bf16x8*)(As + cur * 8192 + (wr * 64 + i * 16 + lr) * BK + quad * 8);
        #pragma unroll
        for (int j = 0; j < 2; j++)
            bf[j] = *(const bf16x8*)(Bs + cur * 2048 + (wc * 32 + j * 16 + lr) * BK + quad * 8);
        #pragma unroll
        for (int i = 0; i < 4; i++)
            #pragma unroll
            for (int j = 0; j < 2; j++)
                acc[i][j] = __builtin_amdgcn_mfma_f32_16x16x32_bf16(af[i], bf[j], acc[i][j], 0, 0, 0);
        __syncthreads();   // buf nxt ready, buf cur free
    }

    // finish ||w||^2: 8 staging threads per row are consecutive lanes
    #pragma unroll
    for (int m = 1; m < 8; m <<= 1) ss += __shfl_xor(ss, m);
    if ((lane & 7) == 0) winv_s[wid * 8 + (lane >> 3)] = SCALE / fmaxf(sqrtf(ss), EPSN);
    __syncthreads();

    // epilogue: scale by S/||w||, partial softmax over this wave's 32 cols
    float wvs[2]; int valid[2];
    #pragma unroll
    for (int j = 0; j < 2; j++) {
        int cg = c0 + wc * 32 + j * 16 + lr;
        valid[j] = (cg < C_CLS);
        wvs[j] = winv_s[wc * 32 + j * 16 + lr];
    }
    int tile2 = blockIdx.y * 2 + wc;
    #pragma unroll
    for (int i = 0; i < 4; i++) {
        #pragma unroll
        for (int r = 0; r < 4; r++) {
            int row_g = m0 + wr * 64 + i * 16 + quad * 4 + r;
            float v0 = valid[0] ? acc[i][0][r] * wvs[0] : -1e30f;
            float v1 = valid[1] ? acc[i][1][r] * wvs[1] : -1e30f;
            float m = fmaxf(v0, v1);
            #pragma unroll
            for (int msk = 1; msk < 16; msk <<= 1) m = fmaxf(m, __shfl_xor(m, msk));
            float s = expf(v0 - m) + expf(v1 - m);
            #pragma unroll
            for (int msk = 1; msk < 16; msk <<= 1) s += __shfl_xor(s, msk);
            if (lr == 0)
                partials[(size_t)row_g * NT2 + tile2] = make_float2(m, s);
        }
    }
}

// ---------- merge partials -> LSE, fused label logit -> mean NLL ----------
__global__ void reduce_loss(const float2* __restrict__ partials,
                            const unsigned short* __restrict__ xnb,
                            const float* __restrict__ w,
                            const int* __restrict__ label,
                            float* __restrict__ out) {
    __shared__ float sm[256], ssum[256];
    __shared__ float tsh;
    int row = blockIdx.x, tid = threadIdx.x;

    // label logit (bf16-consistent with GEMM): 256 threads x 2 elements
    {
        int lab = label[row];
        const float* wr = w + (size_t)lab * D_DIM + tid * 2;
        const unsigned short* xr = xnb + (size_t)row * D_DIM + tid * 2;
        float w0 = wr[0], w1 = wr[1];
        float dot = bf2f(f2bf(w0)) * bf2f(xr[0]) + bf2f(f2bf(w1)) * bf2f(xr[1]);
        float ssl = w0 * w0 + w1 * w1;
        sm[tid] = dot; ssum[tid] = ssl;
        __syncthreads();
        for (int off = 128; off > 0; off >>= 1) {
            if (tid < off) { sm[tid] += sm[tid + off]; ssum[tid] += ssum[tid + off]; }
            __syncthreads();
        }
        if (tid == 0) tsh = sm[0] * SCALE / fmaxf(sqrtf(ssum[0]), EPSN);
        __syncthreads();
    }

    float m = -INFINITY, s = 0.f;
    for (int idx = tid; idx < NT2; idx += 256) {
        float2 p = partials[(size_t)row * NT2 + idx];
        if (p.x > m) { s = s * expf(m - p.x) + p.y; m = p.x; }
        else         { s += p.y * expf(p.x - m); }
    }
    sm[tid] = m; ssum[tid] = s;
    __syncthreads();
    for (int off = 128; off > 0; off >>= 1) {
        if (tid < off) {
            float m2 = sm[tid + off], s2 = ssum[tid + off];
            float mm = fmaxf(m, m2);
            s = s * expf(m - mm) + s2 * expf(m2 - mm);
            m = mm;
            sm[tid] = m; ssum[tid] = s;
        }
        __syncthreads();
    }
    if (tid == 0) {
        float lse = m + logf(s);
        atomicAdd(out, (lse - tsh) * (1.0f / (float)B_ROWS));
    }
}

extern "C" void kernel_launch(void* const* d_in, const int* in_sizes, int n_in,
                              void* d_out, int out_size, void* d_ws, size_t ws_size,
                              hipStream_t stream) {
    const float* x     = (const float*)d_in[0];
    const float* w     = (const float*)d_in[1];
    const int*   label = (const int*)d_in[2];
    float* out = (float*)d_out;

    char* ws = (char*)d_ws;
    unsigned short* xnb = (unsigned short*)ws;                 // 524288 B
    float2* partials    = (float2*)(ws + 524288);              // 512*3126*8 = 12804096 B

    hipMemsetAsync(d_out, 0, sizeof(float), stream);
    normalize_x<<<B_ROWS, 64, 0, stream>>>(x, xnb);
    gemm_fused<<<dim3(2, NTILE), 512, 0, stream>>>(xnb, w, partials);
    reduce_loss<<<B_ROWS, 256, 0, stream>>>(partials, xnb, w, label, out);
}